// Round 7
// baseline (76.264 us; speedup 1.0000x reference)
//
#include <hip/hip_runtime.h>
#include <math.h>
#include <stdint.h>

#define IN_C 64
#define OUT_C 128
#define H 56
#define W 56
#define NB 32
#define HW (H*W)
#define KK 576          // IN_C*9
#define EPS 1e-12f
#define PH 58           // padded rows
#define PW 66           // padded cols in xcl (only 0..57 staged/used by conv)

#define XT_BYTES 45056                   // 6 rows x 58 x 64c x 2B = 44544 (+slack)

typedef _Float16 half8 __attribute__((ext_vector_type(8)));
typedef float f32x4 __attribute__((ext_vector_type(4)));
typedef unsigned int u32;
typedef const u32 __attribute__((address_space(1)))* gp_t;
typedef u32 __attribute__((address_space(3)))* sp_t;

// ---------------- kernel 1: transpose to channels-last padded fp16 ----------
// xcl[n][pr][pc][ c ^ ((pc&7)<<3) ]; also s[n][h][w] = sum_c x^2 (fused).
__global__ __launch_bounds__(256) void k_xpose(const float* __restrict__ x,
                                               _Float16* __restrict__ xcl,
                                               float* __restrict__ s) {
    __shared__ float lds[64][59];
    int n = blockIdx.y, pr = blockIdx.x;
    int tid = threadIdx.x;
    int h = pr - 1;
    bool rowz = (h < 0 || h >= H);
    {
        int w = tid & 63, c4 = tid >> 6;
        if (!rowz && w < 56) {
#pragma unroll
            for (int cg = 0; cg < 16; ++cg) {
                int c = cg * 4 + c4;
                lds[c][w] = x[((size_t)(n * IN_C + c)) * HW + h * W + w];
            }
        }
    }
    __syncthreads();
    int c = tid & 63, pg = tid >> 6;
    _Float16* dst = xcl + ((size_t)n * PH + pr) * PW * IN_C;
#pragma unroll
    for (int pcg = 0; pcg < 15; ++pcg) {
        int pc = pcg * 4 + pg;          // only cols 0..57 are consumed
        if (pc >= 58) break;
        int w = pc - 1;
        bool valid = (!rowz && (unsigned)w < W);
        float val = valid ? lds[c][w] : 0.f;
        dst[(size_t)pc * IN_C + (c ^ ((pc & 7) << 3))] = (_Float16)val;
        float sq = val * val;
#pragma unroll
        for (int off = 32; off > 0; off >>= 1) sq += __shfl_xor(sq, off);
        if (valid && c == 0) s[(size_t)n * HW + h * W + w] = sq;
    }
}

// ---------------- kernel 2: 3x3 neighborhood sum -> 1/x_norm (4 px/thread) --
__global__ __launch_bounds__(256) void k_xnorm(const float* __restrict__ s,
                                               const float* __restrict__ q,
                                               float* __restrict__ inv_xn) {
    int t = blockIdx.x * 256 + threadIdx.x;
    if (t >= NB * HW / 4) return;
    int n = t / (HW / 4);
    int rem = t - n * (HW / 4);
    int p0 = rem * 4;
    int h = p0 / W, w0 = p0 - h * W;
    float q2 = q[0] * 0.01f;
    q2 = q2 * q2;
    const float* sp = s + (size_t)n * HW;
    float a0 = 0.f, a1 = 0.f, a2 = 0.f, a3 = 0.f;
#pragma unroll
    for (int dy = -1; dy <= 1; ++dy) {
        int y = h + dy;
        if ((unsigned)y >= H) continue;
        const float* row = sp + y * W;
        float4 m = *(const float4*)(row + w0);
        float lft = (w0 > 0) ? row[w0 - 1] : 0.f;
        float rgt = (w0 + 4 < W) ? row[w0 + 4] : 0.f;
        a0 += lft + m.x + m.y;
        a1 += m.x + m.y + m.z;
        a2 += m.y + m.z + m.w;
        a3 += m.z + m.w + rgt;
    }
    float4 res;
    res.x = 1.f / (sqrtf(a0 + EPS) + q2);
    res.y = 1.f / (sqrtf(a1 + EPS) + q2);
    res.z = 1.f / (sqrtf(a2 + EPS) + q2);
    res.w = 1.f / (sqrtf(a3 + EPS) + q2);
    *(float4*)(inv_xn + (size_t)n * HW + p0) = res;
}

// ---------------- kernel 3: weight prep (UNswizzled: read from global) ------
// wt[l][v][c] (fp16) = w[v][c][l] / w_norm[v];  e[v] = (p[v]/10)^2
__global__ __launch_bounds__(64) void k_wprep(const float* __restrict__ w,
                                              const float* __restrict__ p,
                                              const float* __restrict__ q,
                                              _Float16* __restrict__ wt,
                                              float* __restrict__ e) {
    int v = blockIdx.x;
    int lane = threadIdx.x;          // lane = c
    const float* wv = w + v * KK;
    float acc = 0.f;
#pragma unroll
    for (int j = 0; j < 9; ++j) {
        float t = wv[lane * 9 + j];
        acc += t * t;
    }
#pragma unroll
    for (int off = 32; off > 0; off >>= 1) acc += __shfl_xor(acc, off);
    float q2 = q[0] * 0.01f;
    q2 = q2 * q2;
    float inv = 1.f / (sqrtf(acc + EPS) + q2);
#pragma unroll
    for (int l = 0; l < 9; ++l) {
        wt[((size_t)l * OUT_C + v) * IN_C + lane] = (_Float16)(wv[lane * 9 + l] * inv);
    }
    if (lane == 0) e[v] = p[v] * p[v] * 0.01f;
}

// ---------------- kernel 4: MFMA conv, weights-in-registers ------------------
// Block: 256 thr (4 waves) = 4 rows x 64 cols x 32 filters (v-quarter).
// Wave = 1 row, 4 m-tiles x 2 v-tiles. B (36 frags, 144 VGPR) loaded ONCE
// from global (L2-hot, 147KB total). x tile in LDS via global_load_lds.
// ONE barrier; main loop = pure ds_read_b128 + MFMA, no fences.
// Grid 1792 blocks @ ~2/CU -> 3.5 staggered generations.
__global__ __launch_bounds__(256, 2) void k_conv_mfma(
    const _Float16* __restrict__ xcl,   // [NB][PH][PW][64] swizzled
    const _Float16* __restrict__ wt,    // [9][128][64] plain
    const float* __restrict__ inv_xn,   // [NB][HW]
    const float* __restrict__ e,        // [128]
    float* __restrict__ out)            // [NB][128][HW]
{
    extern __shared__ __align__(16) char xls[];   // [6][58][64] halves

    int tid = threadIdx.x;
    int wv = tid >> 6;               // wave = row_rel 0..3
    int lane = tid & 63;
    int l15 = lane & 15;
    int kg = lane >> 4;

    // bijective XCD swizzle over 1792 blocks (224 per XCD)
    int flat = (blockIdx.z * 4 + blockIdx.y) * 14 + blockIdx.x;
    int sw = (flat & 7) * 224 + (flat >> 3);
    int n = sw / 56;
    int rem = sw - n * 56;
    int vq = rem / 14;               // v-quarter: v = vq*32 + ...
    int rc = rem - vq * 14;
    int r0 = rc * 4;

    // ---- B fragments for this wave: 2 vt x 9 l x 2 k, from global (L2)
    half8 breg[2][9][2];
#pragma unroll
    for (int vt = 0; vt < 2; ++vt) {
        int v = vq * 32 + vt * 16 + l15;
#pragma unroll
        for (int l = 0; l < 9; ++l)
#pragma unroll
            for (int k = 0; k < 2; ++k)
                breg[vt][l][k] = *(const half8*)(
                    wt + ((size_t)l * OUT_C + v) * IN_C + k * 32 + kg * 8);
    }

    // ---- stage x tile: 6 rows x 58 cols x 64c via global_load_lds (w16)
    {
        const char* xsrc = (const char*)(xcl + ((size_t)n * PH + r0) * PW * IN_C);
#pragma unroll
        for (int i = 0; i < 11; ++i) {
            int j = i * 256 + tid;
            if (j < 2784) {                      // 6 rows x 464 chunks
                int row = j / 464;
                int off = j - row * 464;
                __builtin_amdgcn_global_load_lds(
                    (gp_t)(xsrc + row * (PW * IN_C * 2) + off * 16),
                    (sp_t)(xls + (i * 256 + wv * 64) * 16), 16, 0, 0);
            }
        }
    }
    __syncthreads();                 // the only barrier

    f32x4 acc[4][2];
#pragma unroll
    for (int mt = 0; mt < 4; ++mt)
#pragma unroll
        for (int vt = 0; vt < 2; ++vt) acc[mt][vt] = (f32x4){0.f, 0.f, 0.f, 0.f};

#pragma unroll
    for (int l = 0; l < 9; ++l) {
        int di = l / 3, dj = l % 3;
        int pc0 = l15 + dj;
        const char* xb = xls + ((wv + di) * 58 + pc0) * 128;
        int xkey = (pc0 & 7) << 4;
#pragma unroll
        for (int k = 0; k < 2; ++k) {
            int ko = k * 64 + kg * 16;
            half8 a[4];
#pragma unroll
            for (int mt = 0; mt < 4; ++mt)
                a[mt] = *(const half8*)(xb + mt * 2048 + (ko ^ xkey));
#pragma unroll
            for (int vt = 0; vt < 2; ++vt)
#pragma unroll
                for (int mt = 0; mt < 4; ++mt)
                    acc[mt][vt] = __builtin_amdgcn_mfma_f32_16x16x32_f16(
                        a[mt], breg[vt][l][k], acc[mt][vt], 0, 0, 0);
        }
    }

    // ---- epilogue: lane holds cols mt*16+kg*4..+3 for v = vq*32+vt*16+l15
    int r = r0 + wv;
    const float* ixrow = inv_xn + (size_t)n * HW + r * W;
#pragma unroll
    for (int mt = 0; mt < 4; ++mt) {
        int col0 = mt * 16 + kg * 4;
        if (col0 >= W) continue;         // garbage cols 56..63
        float4 ixn = *(const float4*)(ixrow + col0);
        const float* ixp = &ixn.x;
#pragma unroll
        for (int vt = 0; vt < 2; ++vt) {
            int v = vq * 32 + vt * 16 + l15;
            float ev = e[v];
            float4 res;
            float* rp = &res.x;
#pragma unroll
            for (int j = 0; j < 4; ++j) {
                float z = acc[mt][vt][j] * ixp[j];
                float mag = fabsf(z) + EPS;
                float pw = exp2f(ev * log2f(mag));
                rp[j] = copysignf(pw, z);
            }
            *(float4*)(out + ((size_t)n * OUT_C + v) * HW + r * W + col0) = res;
        }
    }
}

// ---------------- launch ----------------------------------------------------
extern "C" void kernel_launch(void* const* d_in, const int* in_sizes, int n_in,
                              void* d_out, int out_size, void* d_ws, size_t ws_size,
                              hipStream_t stream) {
    const float* x = (const float*)d_in[0];
    const float* w = (const float*)d_in[1];
    const float* p = (const float*)d_in[2];
    const float* q = (const float*)d_in[3];
    float* out = (float*)d_out;

    char* ws = (char*)d_ws;
    float*    s      = (float*)ws;                              // 100352 f
    float*    inv_xn = (float*)(ws + 401408);                   // 100352 f
    float*    e      = (float*)(ws + 802816);                   // 128 f
    _Float16* wt     = (_Float16*)(ws + 803328);                // 9*128*64 h
    _Float16* xcl    = (_Float16*)(ws + 950784);                // 32*58*66*64 h

    k_xpose<<<dim3(PH, NB), dim3(256), 0, stream>>>(x, xcl, s);
    k_xnorm<<<dim3(NB * HW / 4 / 256), dim3(256), 0, stream>>>(s, q, inv_xn);
    k_wprep<<<dim3(OUT_C), dim3(64), 0, stream>>>(w, p, q, wt, e);
    k_conv_mfma<<<dim3(14, 4, NB), dim3(256), XT_BYTES, stream>>>(
        xcl, wt, inv_xn, e, out);
}

// Round 8
// 54.161 us; speedup vs baseline: 1.4081x; 1.4081x over previous
//
#include <hip/hip_runtime.h>
#include <math.h>
#include <stdint.h>

#define IN_C 64
#define OUT_C 128
#define H 56
#define W 56
#define NB 32
#define HW (H*W)
#define KK 576          // IN_C*9
#define EPS 1e-12f
#define PH 58           // padded rows
#define PW 66           // padded cols in xcl (only 0..57 staged/used by conv)

#define XROWB 7424                       // 58 cols x 64c x 2B per staged row
#define XT_BYTES (10 * XROWB)            // 74240
#define WT_BYTES 73728                   // 9 taps x 64v x 64c x 2B (vh half)
#define CONV_LDS (XT_BYTES + WT_BYTES)   // 147968 -> 1 block/CU

typedef _Float16 half8 __attribute__((ext_vector_type(8)));
typedef float f32x4 __attribute__((ext_vector_type(4)));
typedef unsigned int u32;
typedef const u32 __attribute__((address_space(1)))* gp_t;
typedef u32 __attribute__((address_space(3)))* sp_t;

// ---------------- kernel 1: transpose to channels-last padded fp16 ----------
// xcl[n][pr][pc][ c ^ ((pc&7)<<3) ]; also s[n][h][w] = sum_c x^2 (fused).
__global__ __launch_bounds__(256) void k_xpose(const float* __restrict__ x,
                                               _Float16* __restrict__ xcl,
                                               float* __restrict__ s) {
    __shared__ float lds[64][59];
    int n = blockIdx.y, pr = blockIdx.x;
    int tid = threadIdx.x;
    int h = pr - 1;
    bool rowz = (h < 0 || h >= H);
    {
        int w = tid & 63, c4 = tid >> 6;
        if (!rowz && w < 56) {
#pragma unroll
            for (int cg = 0; cg < 16; ++cg) {
                int c = cg * 4 + c4;
                lds[c][w] = x[((size_t)(n * IN_C + c)) * HW + h * W + w];
            }
        }
    }
    __syncthreads();
    int c = tid & 63, pg = tid >> 6;
    _Float16* dst = xcl + ((size_t)n * PH + pr) * PW * IN_C;
#pragma unroll
    for (int pcg = 0; pcg < 15; ++pcg) {
        int pc = pcg * 4 + pg;          // only cols 0..57 are consumed
        if (pc >= 58) break;
        int w = pc - 1;
        bool valid = (!rowz && (unsigned)w < W);
        float val = valid ? lds[c][w] : 0.f;
        dst[(size_t)pc * IN_C + (c ^ ((pc & 7) << 3))] = (_Float16)val;
        float sq = val * val;
#pragma unroll
        for (int off = 32; off > 0; off >>= 1) sq += __shfl_xor(sq, off);
        if (valid && c == 0) s[(size_t)n * HW + h * W + w] = sq;
    }
}

// ---------------- kernel 2: 3x3 neighborhood sum -> 1/x_norm (4 px/thread) --
__global__ __launch_bounds__(256) void k_xnorm(const float* __restrict__ s,
                                               const float* __restrict__ q,
                                               float* __restrict__ inv_xn) {
    int t = blockIdx.x * 256 + threadIdx.x;
    if (t >= NB * HW / 4) return;
    int n = t / (HW / 4);
    int rem = t - n * (HW / 4);
    int p0 = rem * 4;
    int h = p0 / W, w0 = p0 - h * W;
    float q2 = q[0] * 0.01f;
    q2 = q2 * q2;
    const float* sp = s + (size_t)n * HW;
    float a0 = 0.f, a1 = 0.f, a2 = 0.f, a3 = 0.f;
#pragma unroll
    for (int dy = -1; dy <= 1; ++dy) {
        int y = h + dy;
        if ((unsigned)y >= H) continue;
        const float* row = sp + y * W;
        float4 m = *(const float4*)(row + w0);
        float lft = (w0 > 0) ? row[w0 - 1] : 0.f;
        float rgt = (w0 + 4 < W) ? row[w0 + 4] : 0.f;
        a0 += lft + m.x + m.y;
        a1 += m.x + m.y + m.z;
        a2 += m.y + m.z + m.w;
        a3 += m.z + m.w + rgt;
    }
    float4 res;
    res.x = 1.f / (sqrtf(a0 + EPS) + q2);
    res.y = 1.f / (sqrtf(a1 + EPS) + q2);
    res.z = 1.f / (sqrtf(a2 + EPS) + q2);
    res.w = 1.f / (sqrtf(a3 + EPS) + q2);
    *(float4*)(inv_xn + (size_t)n * HW + p0) = res;
}

// ---------------- kernel 3: weight prep (swizzled) ---------------------------
// wt[l][v][ c ^ ((v&7)<<3) ] (fp16) = w[v][c][l] / w_norm[v]
__global__ __launch_bounds__(64) void k_wprep(const float* __restrict__ w,
                                              const float* __restrict__ p,
                                              const float* __restrict__ q,
                                              _Float16* __restrict__ wt,
                                              float* __restrict__ e) {
    int v = blockIdx.x;
    int lane = threadIdx.x;          // lane = c
    const float* wv = w + v * KK;
    float acc = 0.f;
#pragma unroll
    for (int j = 0; j < 9; ++j) {
        float t = wv[lane * 9 + j];
        acc += t * t;
    }
#pragma unroll
    for (int off = 32; off > 0; off >>= 1) acc += __shfl_xor(acc, off);
    float q2 = q[0] * 0.01f;
    q2 = q2 * q2;
    float inv = 1.f / (sqrtf(acc + EPS) + q2);
    int cs = lane ^ ((v & 7) << 3);
#pragma unroll
    for (int l = 0; l < 9; ++l) {
        wt[((size_t)l * OUT_C + v) * IN_C + cs] = (_Float16)(wv[lane * 9 + l] * inv);
    }
    if (lane == 0) e[v] = p[v] * p[v] * 0.01f;
}

// ---------------- kernel 4: MFMA conv, static LDS + cross-tap prefetch ------
// Block: 512 thr (8 waves) = 8 rows x 64 cols x 64 filters (vh half).
// x (10 rows) + ALL 9 weight taps staged once; ONE barrier; 9 unrolled taps
// with A-fragments double-buffered in regs (tap l+1 reads fly under tap l's
// MFMAs). Wave = 1 row, 4 m-tiles x 4 v-tiles.
__global__ __launch_bounds__(512, 2) void k_conv_mfma(
    const _Float16* __restrict__ xcl,   // [NB][PH][PW][64] swizzled
    const _Float16* __restrict__ wt,    // [9][128][64] swizzled
    const float* __restrict__ inv_xn,   // [NB][HW]
    const float* __restrict__ e,        // [128]
    float* __restrict__ out)            // [NB][128][HW]
{
    extern __shared__ __align__(16) char smem[];
    char* xls = smem;                    // [10][58][64] halves
    char* wls = smem + XT_BYTES;         // [9][64][64] halves (this vh half)

    int tid = threadIdx.x;
    int wv = tid >> 6;               // wave = row_rel 0..7
    int lane = tid & 63;
    int l15 = lane & 15;
    int kg = lane >> 4;

    // bijective XCD swizzle over 448 blocks (56 per XCD)
    int flat = (blockIdx.z * 2 + blockIdx.y) * 7 + blockIdx.x;
    int sw = (flat & 7) * 56 + (flat >> 3);
    int n = sw / 14;
    int rem = sw - n * 14;
    int vh = rem / 7;
    int r0 = (rem - vh * 7) * 8;

    // ---- stage x: 10 rows x 464 chunks (threads 0..463 per row)
    {
        const char* xsrc = (const char*)(xcl + ((size_t)n * PH + r0) * PW * IN_C);
        if (tid < 464) {
#pragma unroll
            for (int row = 0; row < 10; ++row)
                __builtin_amdgcn_global_load_lds(
                    (gp_t)(xsrc + row * (PW * IN_C * 2) + tid * 16),
                    (sp_t)(xls + row * XROWB + (wv * 64) * 16), 16, 0, 0);
        }
    }
    // ---- stage w: 9 taps x 512 chunks (tap-contiguous 8KB each)
    {
        const char* wsrc = (const char*)(wt + (size_t)vh * 64 * IN_C);
#pragma unroll
        for (int l = 0; l < 9; ++l)
            __builtin_amdgcn_global_load_lds(
                (gp_t)(wsrc + (size_t)l * OUT_C * IN_C * 2 + tid * 16),
                (sp_t)(wls + l * 8192 + (wv * 64) * 16), 16, 0, 0);
    }
    __syncthreads();                 // the only barrier

    f32x4 acc[4][4];
#pragma unroll
    for (int mt = 0; mt < 4; ++mt)
#pragma unroll
        for (int vt = 0; vt < 4; ++vt) acc[mt][vt] = (f32x4){0.f, 0.f, 0.f, 0.f};

    // A-fragment double buffer: [buf][k][mt] (indices compile-time via unroll)
    half8 areg[2][2][4];
    {
        int pc0 = l15;                       // tap 0: di=0, dj=0
        const char* xb = xls + (wv * 58 + pc0) * 128;
        int xkey = (pc0 & 7) << 4;
#pragma unroll
        for (int k = 0; k < 2; ++k)
#pragma unroll
            for (int mt = 0; mt < 4; ++mt)
                areg[0][k][mt] = *(const half8*)(
                    xb + mt * 2048 + ((k * 64 + kg * 16) ^ xkey));
    }

#pragma unroll
    for (int l = 0; l < 9; ++l) {
        int cur = l & 1, nxt = cur ^ 1;
        // prefetch tap l+1 A-frags (fly under this tap's MFMAs)
        if (l < 8) {
            int lx = l + 1;
            int di = lx / 3, dj = lx % 3;
            int pc0 = l15 + dj;
            const char* xb = xls + ((wv + di) * 58 + pc0) * 128;
            int xkey = (pc0 & 7) << 4;
#pragma unroll
            for (int k = 0; k < 2; ++k)
#pragma unroll
                for (int mt = 0; mt < 4; ++mt)
                    areg[nxt][k][mt] = *(const half8*)(
                        xb + mt * 2048 + ((k * 64 + kg * 16) ^ xkey));
        }
        // B frags for tap l
        const char* wb = wls + l * 8192 + l15 * 128;
        int wkey = (l15 & 7) << 4;
        half8 b[2][4];
#pragma unroll
        for (int k = 0; k < 2; ++k)
#pragma unroll
            for (int vt = 0; vt < 4; ++vt)
                b[k][vt] = *(const half8*)(
                    wb + vt * 2048 + ((k * 64 + kg * 16) ^ wkey));

        __builtin_amdgcn_s_setprio(1);
#pragma unroll
        for (int k = 0; k < 2; ++k)
#pragma unroll
            for (int vt = 0; vt < 4; ++vt)
#pragma unroll
                for (int mt = 0; mt < 4; ++mt)
                    acc[mt][vt] = __builtin_amdgcn_mfma_f32_16x16x32_f16(
                        areg[cur][k][mt], b[k][vt], acc[mt][vt], 0, 0, 0);
        __builtin_amdgcn_s_setprio(0);
    }

    // ---- epilogue: lane holds cols mt*16+kg*4..+3 for v = vh*64+vt*16+l15
    int r = r0 + wv;
    const float* ixrow = inv_xn + (size_t)n * HW + r * W;
#pragma unroll
    for (int mt = 0; mt < 4; ++mt) {
        int col0 = mt * 16 + kg * 4;
        if (col0 >= W) continue;         // garbage cols 56..63
        float4 ixn = *(const float4*)(ixrow + col0);
        const float* ixp = &ixn.x;
#pragma unroll
        for (int vt = 0; vt < 4; ++vt) {
            int v = vh * 64 + vt * 16 + l15;
            float ev = e[v];
            float4 res;
            float* rp = &res.x;
#pragma unroll
            for (int j = 0; j < 4; ++j) {
                float z = acc[mt][vt][j] * ixp[j];
                float mag = fabsf(z) + EPS;
                float pw = exp2f(ev * log2f(mag));
                rp[j] = copysignf(pw, z);
            }
            *(float4*)(out + ((size_t)n * OUT_C + v) * HW + r * W + col0) = res;
        }
    }
}

// ---------------- launch ----------------------------------------------------
extern "C" void kernel_launch(void* const* d_in, const int* in_sizes, int n_in,
                              void* d_out, int out_size, void* d_ws, size_t ws_size,
                              hipStream_t stream) {
    const float* x = (const float*)d_in[0];
    const float* w = (const float*)d_in[1];
    const float* p = (const float*)d_in[2];
    const float* q = (const float*)d_in[3];
    float* out = (float*)d_out;

    char* ws = (char*)d_ws;
    float*    s      = (float*)ws;                              // 100352 f
    float*    inv_xn = (float*)(ws + 401408);                   // 100352 f
    float*    e      = (float*)(ws + 802816);                   // 128 f
    _Float16* wt     = (_Float16*)(ws + 803328);                // 9*128*64 h
    _Float16* xcl    = (_Float16*)(ws + 950784);                // 32*58*66*64 h

    hipFuncSetAttribute((const void*)k_conv_mfma,
                        hipFuncAttributeMaxDynamicSharedMemorySize, CONV_LDS);

    k_xpose<<<dim3(PH, NB), dim3(256), 0, stream>>>(x, xcl, s);
    k_xnorm<<<dim3(NB * HW / 4 / 256), dim3(256), 0, stream>>>(s, q, inv_xn);
    k_wprep<<<dim3(OUT_C), dim3(64), 0, stream>>>(w, p, q, wt, e);
    k_conv_mfma<<<dim3(7, 2, NB), dim3(512), CONV_LDS, stream>>>(
        xcl, wt, inv_xn, e, out);
}

// Round 9
// 52.106 us; speedup vs baseline: 1.4636x; 1.0394x over previous
//
#include <hip/hip_runtime.h>
#include <math.h>
#include <stdint.h>

#define IN_C 64
#define OUT_C 128
#define H 56
#define W 56
#define NB 32
#define HW (H*W)
#define KK 576          // IN_C*9
#define EPS 1e-12f
#define PH 58           // padded rows
#define PW 66           // padded cols in xcl (only 0..57 staged/used by conv)

#define XT_BYTES 44544                   // 6 rows x 58 cols x 64c x 2B
#define WT_BYTES 16384                   // 128v x 64c x 2B (one tap)
#define CONV_LDS (XT_BYTES + 2 * WT_BYTES)   // 77312 -> 2 blocks/CU

typedef _Float16 half8 __attribute__((ext_vector_type(8)));
typedef float f32x4 __attribute__((ext_vector_type(4)));
typedef unsigned int u32;
typedef const u32 __attribute__((address_space(1)))* gp_t;
typedef u32 __attribute__((address_space(3)))* sp_t;

// ---------------- kernel 1: transpose to channels-last padded fp16 ----------
// xcl[n][pr][pc][ c ^ ((pc&7)<<3) ]; also s[n][h][w] = sum_c x^2 (fused).
__global__ __launch_bounds__(256) void k_xpose(const float* __restrict__ x,
                                               _Float16* __restrict__ xcl,
                                               float* __restrict__ s) {
    __shared__ float lds[64][59];
    int n = blockIdx.y, pr = blockIdx.x;
    int tid = threadIdx.x;
    int h = pr - 1;
    bool rowz = (h < 0 || h >= H);
    {
        int w = tid & 63, c4 = tid >> 6;
        if (!rowz && w < 56) {
#pragma unroll
            for (int cg = 0; cg < 16; ++cg) {
                int c = cg * 4 + c4;
                lds[c][w] = x[((size_t)(n * IN_C + c)) * HW + h * W + w];
            }
        }
    }
    __syncthreads();
    int c = tid & 63, pg = tid >> 6;
    _Float16* dst = xcl + ((size_t)n * PH + pr) * PW * IN_C;
#pragma unroll
    for (int pcg = 0; pcg < 15; ++pcg) {
        int pc = pcg * 4 + pg;          // only cols 0..57 are consumed
        if (pc >= 58) break;
        int w = pc - 1;
        bool valid = (!rowz && (unsigned)w < W);
        float val = valid ? lds[c][w] : 0.f;
        dst[(size_t)pc * IN_C + (c ^ ((pc & 7) << 3))] = (_Float16)val;
        float sq = val * val;
#pragma unroll
        for (int off = 32; off > 0; off >>= 1) sq += __shfl_xor(sq, off);
        if (valid && c == 0) s[(size_t)n * HW + h * W + w] = sq;
    }
}

// ---------------- kernel 2: 3x3 neighborhood sum -> 1/x_norm (4 px/thread) --
__global__ __launch_bounds__(256) void k_xnorm(const float* __restrict__ s,
                                               const float* __restrict__ q,
                                               float* __restrict__ inv_xn) {
    int t = blockIdx.x * 256 + threadIdx.x;
    if (t >= NB * HW / 4) return;
    int n = t / (HW / 4);
    int rem = t - n * (HW / 4);
    int p0 = rem * 4;
    int h = p0 / W, w0 = p0 - h * W;
    float q2 = q[0] * 0.01f;
    q2 = q2 * q2;
    const float* sp = s + (size_t)n * HW;
    float a0 = 0.f, a1 = 0.f, a2 = 0.f, a3 = 0.f;
#pragma unroll
    for (int dy = -1; dy <= 1; ++dy) {
        int y = h + dy;
        if ((unsigned)y >= H) continue;
        const float* row = sp + y * W;
        float4 m = *(const float4*)(row + w0);
        float lft = (w0 > 0) ? row[w0 - 1] : 0.f;
        float rgt = (w0 + 4 < W) ? row[w0 + 4] : 0.f;
        a0 += lft + m.x + m.y;
        a1 += m.x + m.y + m.z;
        a2 += m.y + m.z + m.w;
        a3 += m.z + m.w + rgt;
    }
    float4 res;
    res.x = 1.f / (sqrtf(a0 + EPS) + q2);
    res.y = 1.f / (sqrtf(a1 + EPS) + q2);
    res.z = 1.f / (sqrtf(a2 + EPS) + q2);
    res.w = 1.f / (sqrtf(a3 + EPS) + q2);
    *(float4*)(inv_xn + (size_t)n * HW + p0) = res;
}

// ---------------- kernel 3: weight prep (swizzled) ---------------------------
// wt[l][v][ c ^ ((v&7)<<3) ] (fp16) = w[v][c][l] / w_norm[v]
__global__ __launch_bounds__(64) void k_wprep(const float* __restrict__ w,
                                              const float* __restrict__ p,
                                              const float* __restrict__ q,
                                              _Float16* __restrict__ wt,
                                              float* __restrict__ e) {
    int v = blockIdx.x;
    int lane = threadIdx.x;          // lane = c
    const float* wv = w + v * KK;
    float acc = 0.f;
#pragma unroll
    for (int j = 0; j < 9; ++j) {
        float t = wv[lane * 9 + j];
        acc += t * t;
    }
#pragma unroll
    for (int off = 32; off > 0; off >>= 1) acc += __shfl_xor(acc, off);
    float q2 = q[0] * 0.01f;
    q2 = q2 * q2;
    float inv = 1.f / (sqrtf(acc + EPS) + q2);
    int cs = lane ^ ((v & 7) << 3);
#pragma unroll
    for (int l = 0; l < 9; ++l) {
        wt[((size_t)l * OUT_C + v) * IN_C + cs] = (_Float16)(wv[lane * 9 + l] * inv);
    }
    if (lane == 0) e[v] = p[v] * p[v] * 0.01f;
}

// ---------------- kernel 4: MFMA conv, counted-vmcnt streaming ---------------
// R6 structure + T4: raw s_barrier with s_waitcnt vmcnt(2) keeps the
// next-tap weight DMA in flight across the barrier (no vmcnt(0) drain).
// Two barriers/tap (dbuf overwrite protection). T5 setprio around MFMAs.
__global__ __launch_bounds__(512, 4) void k_conv_mfma(
    const _Float16* __restrict__ xcl,   // [NB][PH][PW][64] swizzled
    const _Float16* __restrict__ wt,    // [9][128][64] swizzled
    const float* __restrict__ inv_xn,   // [NB][HW]
    const float* __restrict__ e,        // [128]
    float* __restrict__ out)            // [NB][128][HW]
{
    extern __shared__ __align__(16) char smem[];
    char* xls = smem;                    // [6][58][64] halves (swizzled cols)
    char* wls = smem + XT_BYTES;         // 2 x [128][64] halves

    int tid = threadIdx.x;
    int wv = tid >> 6;
    int lane = tid & 63;
    int l15 = lane & 15;
    int kg = lane >> 4;

    // bijective XCD swizzle: 448 blocks, 8 XCDs, 4 images per XCD
    int flat = blockIdx.y * 14 + blockIdx.x;
    int sw = (flat & 7) * 56 + (flat >> 3);
    int n = sw / 14;
    int rc = sw - n * 14;
    int r0 = rc * 4;
    int row_rel = wv >> 1;
    int vh = wv & 1;
    int wave_chunk = wv * 64;

    // ---- prologue: DMA x tile (6 rows x 58 cols) + w tap 0
    {
        const char* xsrc = (const char*)(xcl + ((size_t)n * PH + r0) * PW * IN_C);
#pragma unroll
        for (int i = 0; i < 6; ++i) {
            int j = i * 512 + tid;
            if (j < 2784) {                       // 6*464 chunks
                int row = j / 464;
                int off = j - row * 464;
                __builtin_amdgcn_global_load_lds(
                    (gp_t)(xsrc + row * (PW * IN_C * 2) + off * 16),
                    (sp_t)(xls + (i * 512 + wave_chunk) * 16), 16, 0, 0);
            }
        }
        const char* wsrc = (const char*)wt;
#pragma unroll
        for (int i = 0; i < 2; ++i)
            __builtin_amdgcn_global_load_lds(
                (gp_t)(wsrc + (i * 512 + tid) * 16),
                (sp_t)(wls + (i * 512 + wave_chunk) * 16), 16, 0, 0);
    }

    f32x4 acc[4][4];
#pragma unroll
    for (int mt = 0; mt < 4; ++mt)
#pragma unroll
        for (int vt = 0; vt < 4; ++vt) acc[mt][vt] = (f32x4){0.f, 0.f, 0.f, 0.f};

#pragma unroll
    for (int l = 0; l < 9; ++l) {
        // issue next tap's weight DMA (stays in flight across the barrier)
        if (l < 8) {
            const char* wsrc = (const char*)wt + (size_t)(l + 1) * WT_BYTES;
            char* wdst = wls + ((l + 1) & 1) * WT_BYTES;
            __builtin_amdgcn_global_load_lds(
                (gp_t)(wsrc + tid * 16),
                (sp_t)(wdst + wave_chunk * 16), 16, 0, 0);
            __builtin_amdgcn_global_load_lds(
                (gp_t)(wsrc + (512 + tid) * 16),
                (sp_t)(wdst + (512 + wave_chunk) * 16), 16, 0, 0);
        }
        // T4: wait all but the 2 newest (= next tap's pair); final tap: all
        if (l < 8) asm volatile("s_waitcnt vmcnt(2)" ::: "memory");
        else       asm volatile("s_waitcnt vmcnt(0)" ::: "memory");
        __builtin_amdgcn_s_barrier();    // w(l) visible to all waves

        int di = l / 3, dj = l % 3;
        int pc0 = l15 + dj;
        const char* xb = xls + ((row_rel + di) * 58 + pc0) * 128;
        int xkey = (pc0 & 7) << 4;
        const char* wb = wls + (l & 1) * WT_BYTES + (vh * 64 + l15) * 128;
        int wkey = (l15 & 7) << 4;

#pragma unroll
        for (int k = 0; k < 2; ++k) {
            int ko = k * 64 + kg * 16;
            half8 a[4];
#pragma unroll
            for (int mt = 0; mt < 4; ++mt)
                a[mt] = *(const half8*)(xb + mt * 2048 + (ko ^ xkey));
            half8 b[4];
#pragma unroll
            for (int vt = 0; vt < 4; ++vt)
                b[vt] = *(const half8*)(wb + vt * 2048 + (ko ^ wkey));
            __builtin_amdgcn_s_setprio(1);
#pragma unroll
            for (int vt = 0; vt < 4; ++vt)
#pragma unroll
                for (int mt = 0; mt < 4; ++mt)
                    acc[mt][vt] = __builtin_amdgcn_mfma_f32_16x16x32_f16(
                        a[mt], b[vt], acc[mt][vt], 0, 0, 0);
            __builtin_amdgcn_s_setprio(0);
        }
        __builtin_amdgcn_s_barrier();    // all reads of wls[(l+1)&1] done
    }

    // ---- epilogue: lane holds cols mt*16+kg*4..+3 for v = vh*64+vt*16+l15
    int r = r0 + row_rel;
    const float* ixrow = inv_xn + (size_t)n * HW + r * W;
#pragma unroll
    for (int mt = 0; mt < 4; ++mt) {
        int col0 = mt * 16 + kg * 4;
        if (col0 >= W) continue;         // garbage cols 56..63
        float4 ixn = *(const float4*)(ixrow + col0);
        const float* ixp = &ixn.x;
#pragma unroll
        for (int vt = 0; vt < 4; ++vt) {
            int v = vh * 64 + vt * 16 + l15;
            float ev = e[v];
            float4 res;
            float* rp = &res.x;
            if (fabsf(ev - 2.0f) < 1e-4f) {
                // exponent == 2 (this input's p): square, no transcendentals
#pragma unroll
                for (int j = 0; j < 4; ++j) {
                    float z = acc[mt][vt][j] * ixp[j];
                    float mag = fabsf(z) + EPS;
                    rp[j] = copysignf(mag * mag, z);
                }
            } else {
#pragma unroll
                for (int j = 0; j < 4; ++j) {
                    float z = acc[mt][vt][j] * ixp[j];
                    float mag = fabsf(z) + EPS;
                    float pw = exp2f(ev * log2f(mag));
                    rp[j] = copysignf(pw, z);
                }
            }
            *(float4*)(out + ((size_t)n * OUT_C + v) * HW + r * W + col0) = res;
        }
    }
}

// ---------------- launch ----------------------------------------------------
extern "C" void kernel_launch(void* const* d_in, const int* in_sizes, int n_in,
                              void* d_out, int out_size, void* d_ws, size_t ws_size,
                              hipStream_t stream) {
    const float* x = (const float*)d_in[0];
    const float* w = (const float*)d_in[1];
    const float* p = (const float*)d_in[2];
    const float* q = (const float*)d_in[3];
    float* out = (float*)d_out;

    char* ws = (char*)d_ws;
    float*    s      = (float*)ws;                              // 100352 f
    float*    inv_xn = (float*)(ws + 401408);                   // 100352 f
    float*    e      = (float*)(ws + 802816);                   // 128 f
    _Float16* wt     = (_Float16*)(ws + 803328);                // 9*128*64 h
    _Float16* xcl    = (_Float16*)(ws + 950784);                // 32*58*66*64 h

    hipFuncSetAttribute((const void*)k_conv_mfma,
                        hipFuncAttributeMaxDynamicSharedMemorySize, CONV_LDS);

    k_xpose<<<dim3(PH, NB), dim3(256), 0, stream>>>(x, xcl, s);
    k_xnorm<<<dim3(NB * HW / 4 / 256), dim3(256), 0, stream>>>(s, q, inv_xn);
    k_wprep<<<dim3(OUT_C), dim3(64), 0, stream>>>(w, p, q, wt, e);
    k_conv_mfma<<<dim3(14, NB), dim3(512), CONV_LDS, stream>>>(
        xcl, wt, inv_xn, e, out);
}